// Round 5
// baseline (91.881 us; speedup 1.0000x reference)
//
#include <hip/hip_runtime.h>

#define PNUM   512
#define LB     512        // L_PREDS * BATCH
#define NCHUNK 4
#define JCHUNK 128        // j values per chunk
#define NSS    32         // 32 double-iterations (64 s-steps, 2 j per s)

// smooth_l1 accumulate for one (pred_pt, gt_pt) pair, split accumulators
#define SL1(px, py, qx, qy, accA, accB) {                        \
    float dx_ = (px) - (qx), dy_ = (py) - (qy);                  \
    float tx_ = fminf(fabsf(dx_), 1.0f);                         \
    float ty_ = fminf(fabsf(dy_), 1.0f);                         \
    accA = fmaf(tx_, fmaf(-0.5f, tx_, fabsf(dx_)), accA);        \
    accB = fmaf(ty_, fmaf(-0.5f, ty_, fabsf(dy_)), accB); }

// 8 point-pair evals for one s-step (4 shifts x 2 j), given window q0..q4
#define BODY(P, W0, W1, W2)                                      \
    SL1((P).x, (P).y, (W0).x, (W0).y, a0, b0);                   \
    SL1((P).z, (P).w, (W0).z, (W0).w, a0, b0);                   \
    SL1((P).x, (P).y, (W0).z, (W0).w, a1, b1);                   \
    SL1((P).z, (P).w, (W1).x, (W1).y, a1, b1);                   \
    SL1((P).x, (P).y, (W1).x, (W1).y, a2, b2);                   \
    SL1((P).z, (P).w, (W1).z, (W1).w, a2, b2);                   \
    SL1((P).x, (P).y, (W1).z, (W1).w, a3, b3);                   \
    SL1((P).z, (P).w, (W2).x, (W2).y, a3, b3);

// Kernel 1: block = (lb, j-chunk). 128 threads; thread t owns shifts 4t..4t+3.
// Writes partial[chunk][lb][i] = sum over its j-chunk of sl1 pairs (no min here).
// gt stored doubled + parity-split (sgE/sgO) so the stride-2-float4 gather
// becomes two stride-1 conflict-free ds_read_b128 streams.
__global__ __launch_bounds__(128, 4)
void poly_partial_kernel(const float* __restrict__ pred,   // (2,256,512,2)
                         const float* __restrict__ gt,     // (256,512,2)
                         float* __restrict__ partial)      // (4,512,512)
{
    __shared__ float4 sgE[260];   // even float4s of doubled gt ring (+pads)
    __shared__ float4 sgO[260];   // odd  float4s (+pads)
    __shared__ float4 spc[66];    // pred j-chunk: 64 float4s (+pads)

    const int bid   = blockIdx.x;       // 0..2047
    const int chunk = bid & 3;
    const int lb    = bid >> 2;         // 0..511
    const int b     = lb & 255;
    const int t     = threadIdx.x;      // 0..127

    const int KC = chunk * (JCHUNK / 2);  // float4 (point-pair) base of chunk: 0,64,128,192
    const int KH = KC >> 1;               // 0,32,64,96

    const float4* pp4 = (const float4*)(pred + (size_t)lb * PNUM * 2);
    const float4* gp4 = (const float4*)(gt   + (size_t)b  * PNUM * 2);

    // stage gt doubled, parity-split: sgE[k] = gv4[(2k)&255], sgO[k] = gv4[(2k+1)&255]
    float4 ge = gp4[2 * t];
    float4 go = gp4[2 * t + 1];
    sgE[t]       = ge;  sgE[t + 128] = ge;
    sgO[t]       = go;  sgO[t + 128] = go;
    if (t < 4) { sgE[256 + t] = ge; sgO[256 + t] = go; }   // pads (t=0..3 hold gv4[0..7])
    if (t < 64)  spc[t] = pp4[KC + t];
    if (t < 2)   spc[64 + t] = pp4[KC];                    // pad (value unused)
    __syncthreads();

    float a0 = 0.f, a1 = 0.f, a2 = 0.f, a3 = 0.f;
    float b0 = 0.f, b1 = 0.f, b2 = 0.f, b3 = 0.f;

    const int i0 = t + KH;     // base index into sgE/sgO for this thread
    // window: doubled-ring float4 index g = 2t + KC + s; q0..q4 = points 4t+jc+2s .. +4
    float4 W0 = sgE[i0];           // g even
    float4 W1 = sgO[i0];           // g+1
    float4 W2 = sgE[i0 + 1];       // g+2
    float4 P  = spc[0];

    #pragma unroll 4
    for (int ss = 0; ss < NSS; ++ss) {
        // s = 2ss: prefetch g+3 (odd) and next P
        {
            const float4 Wn = sgO[i0 + ss + 1];
            const float4 Pn = spc[2 * ss + 1];
            BODY(P, W0, W1, W2)
            W0 = W1; W1 = W2; W2 = Wn; P = Pn;
        }
        // s = 2ss+1: prefetch g+3 (even) and next P
        {
            const float4 Wn = sgE[i0 + ss + 2];
            const float4 Pn = spc[2 * ss + 2];
            BODY(P, W0, W1, W2)
            W0 = W1; W1 = W2; W2 = Wn; P = Pn;
        }
    }

    // per-shift partial sums for this j-chunk -> coalesced float4 store
    float4 r = make_float4(a0 + b0, a1 + b1, a2 + b2, a3 + b3);
    ((float4*)partial)[(chunk * LB + lb) * 128 + t] = r;
}

// Kernel 2: sum the 4 j-chunk partials per (lb, i), then min over i.
__global__ __launch_bounds__(512)
void poly_combine_kernel(const float* __restrict__ partial,  // (4,512,512)
                         float* __restrict__ bmin)           // (512,)
{
    const int lb = blockIdx.x;
    const int t  = threadIdx.x;   // = shift i

    float v = partial[(0 * LB + lb) * PNUM + t]
            + partial[(1 * LB + lb) * PNUM + t]
            + partial[(2 * LB + lb) * PNUM + t]
            + partial[(3 * LB + lb) * PNUM + t];

    #pragma unroll
    for (int d = 1; d < 64; d <<= 1)
        v = fminf(v, __shfl_xor(v, d, 64));

    __shared__ float s[8];
    if ((t & 63) == 0) s[t >> 6] = v;
    __syncthreads();
    if (t == 0) {
        float mm = s[0];
        #pragma unroll
        for (int k = 1; k < 8; ++k) mm = fminf(mm, s[k]);
        bmin[lb] = mm;
    }
}

// Kernel 3: loss = sum(bmin) / (512 * 512)
__global__ __launch_bounds__(512)
void poly_match_finalize(const float* __restrict__ bmin,
                         float* __restrict__ out)
{
    const int t = threadIdx.x;
    float v = bmin[t];
    #pragma unroll
    for (int d = 1; d < 64; d <<= 1)
        v += __shfl_xor(v, d, 64);

    __shared__ float s[8];
    if ((t & 63) == 0) s[t >> 6] = v;
    __syncthreads();
    if (t == 0) {
        float tot = 0.0f;
        #pragma unroll
        for (int k = 0; k < 8; ++k) tot += s[k];
        out[0] = tot * (1.0f / (512.0f * 512.0f));
    }
}

extern "C" void kernel_launch(void* const* d_in, const int* in_sizes, int n_in,
                              void* d_out, int out_size, void* d_ws, size_t ws_size,
                              hipStream_t stream)
{
    const float* pred = (const float*)d_in[0];  // (2,256,512,2) fp32
    const float* gt   = (const float*)d_in[1];  // (256,512,2)   fp32
    float* out     = (float*)d_out;             // scalar fp32
    float* partial = (float*)d_ws;                         // 4*512*512 floats = 4 MB
    float* bmin    = (float*)d_ws + NCHUNK * LB * PNUM;    // 512 floats

    poly_partial_kernel<<<NCHUNK * LB, 128, 0, stream>>>(pred, gt, partial);
    poly_combine_kernel<<<LB, PNUM, 0, stream>>>(partial, bmin);
    poly_match_finalize<<<1, PNUM, 0, stream>>>(bmin, out);
}

// Round 7
// 86.698 us; speedup vs baseline: 1.0598x; 1.0598x over previous
//
#include <hip/hip_runtime.h>

#define PNUM 512
#define LB   512   // L_PREDS * BATCH

// smooth_l1 for one (x,y) point pair, split accumulators.
// sl1(x) = t*(|x| - 0.5t), t = min(|x|,1) — 4 VALU/comp if abs folds to modifiers.
#define SL1(px, py, qx, qy, accA, accB) {                        \
    float dx_ = (px) - (qx), dy_ = (py) - (qy);                  \
    float tx_ = fminf(fabsf(dx_), 1.0f);                         \
    float ty_ = fminf(fabsf(dy_), 1.0f);                         \
    accA = fmaf(tx_, fmaf(-0.5f, tx_, fabsf(dx_)), accA);        \
    accB = fmaf(ty_, fmaf(-0.5f, ty_, fabsf(dy_)), accB); }

// One s-step: 8 shifts x 2 j = 16 point evals. Window W0..W4 = 5 consecutive
// gt float4s (10 points); Pv = pred float4 (2 points, j even/odd).
#define BODY(Pv, W0, W1, W2, W3, W4)                             \
    SL1((Pv).x,(Pv).y,(W0).x,(W0).y,a0,b0);                      \
    SL1((Pv).z,(Pv).w,(W0).z,(W0).w,a0,b0);                      \
    SL1((Pv).x,(Pv).y,(W0).z,(W0).w,a1,b1);                      \
    SL1((Pv).z,(Pv).w,(W1).x,(W1).y,a1,b1);                      \
    SL1((Pv).x,(Pv).y,(W1).x,(W1).y,a2,b2);                      \
    SL1((Pv).z,(Pv).w,(W1).z,(W1).w,a2,b2);                      \
    SL1((Pv).x,(Pv).y,(W1).z,(W1).w,a3,b3);                      \
    SL1((Pv).z,(Pv).w,(W2).x,(W2).y,a3,b3);                      \
    SL1((Pv).x,(Pv).y,(W2).x,(W2).y,a4,b4);                      \
    SL1((Pv).z,(Pv).w,(W2).z,(W2).w,a4,b4);                      \
    SL1((Pv).x,(Pv).y,(W2).z,(W2).w,a5,b5);                      \
    SL1((Pv).z,(Pv).w,(W3).x,(W3).y,a5,b5);                      \
    SL1((Pv).x,(Pv).y,(W3).x,(W3).y,a6,b6);                      \
    SL1((Pv).z,(Pv).w,(W3).z,(W3).w,a6,b6);                      \
    SL1((Pv).x,(Pv).y,(W3).z,(W3).w,a7,b7);                      \
    SL1((Pv).z,(Pv).w,(W4).x,(W4).y,a7,b7);

// Block = (l,b). 8 waves; wave w owns j in [64w, 64w+64); lane l owns shifts
// 8l..8l+7. gt ring (1024 pts doubled) stored parity-split by float4-index
// mod 4 (sg[p][k] = ring_f4[4k+p]) so the stride-4-float4 gather becomes
// stride-1 conflict-free ds_read_b128 with compile-time sub-array selection.
__global__ __launch_bounds__(512, 4)
void poly_match_kernel(const float* __restrict__ pred,   // (2,256,512,2)
                       const float* __restrict__ gt,     // (256,512,2)
                       float* __restrict__ bmin)         // (512,)
{
    __shared__ float4 sg[4][132];     // parity-split doubled gt ring (+pads)
    __shared__ float4 spred[258];     // full pred, float4 view (+pad)
    __shared__ float  part2[64][64];  // [w*8+r][lane] per-wave shift partials
    __shared__ float  swave[8];

    const int lb = blockIdx.x;
    const int b  = lb & 255;
    const int t  = threadIdx.x;       // 0..511
    const int w  = t >> 6;            // wave 0..7
    const int l  = t & 63;            // lane

    const float4* pp4 = (const float4*)(pred + (size_t)lb * PNUM * 2);
    const float4* gp4 = (const float4*)(gt   + (size_t)b  * PNUM * 2);

    // stage: ring_f4[m] = gt_f4[m & 255], m = t covers 0..511
    sg[t & 3][t >> 2] = gp4[t & 255];
    if (t < 8)   sg[t & 3][128 + (t >> 2)] = gp4[t];   // pads k=128,129 (ring period 256)
    if (t < 256) spred[t] = pp4[t];
    if (t == 0)  spred[256] = pp4[0];                  // dead-prefetch pad
    __syncthreads();

    const int A  = l + 8 * w;     // gather base: k index into sg[p][.]
    const int pb = 32 * w;        // pred float4 base for this wave's j-range

    float a0=0.f,a1=0.f,a2=0.f,a3=0.f,a4=0.f,a5=0.f,a6=0.f,a7=0.f;
    float b0=0.f,b1=0.f,b2=0.f,b3=0.f,b4=0.f,b5=0.f,b6=0.f,b7=0.f;

    float4 v0 = sg[0][A];
    float4 v1 = sg[1][A];
    float4 v2 = sg[2][A];
    float4 v3 = sg[3][A];
    float4 v4 = sg[0][A + 1];
    float4 P  = spred[pb];

    for (int q = 0; q < 8; ++q) {   // s = 4q..4q+3; j advances 2 per s-step
        const float4 n0  = sg[1][A + q + 1];
        const float4 Pn  = spred[pb + 4 * q + 1];
        BODY(P, v0, v1, v2, v3, v4)

        const float4 n1  = sg[2][A + q + 1];
        const float4 Pn2 = spred[pb + 4 * q + 2];
        BODY(Pn, v1, v2, v3, v4, n0)

        const float4 n2  = sg[3][A + q + 1];
        const float4 Pn3 = spred[pb + 4 * q + 3];
        BODY(Pn2, v2, v3, v4, n0, n1)

        const float4 n3  = sg[0][A + q + 2];
        const float4 Pn4 = spred[pb + 4 * q + 4];
        BODY(Pn3, v3, v4, n0, n1, n2)

        v0 = v4; v1 = n0; v2 = n1; v3 = n2; v4 = n3; P = Pn4;
    }

    // per-wave j-partials: row w*8+r, col l  (conflict-free: lanes -> consecutive banks)
    part2[w * 8 + 0][l] = a0 + b0;
    part2[w * 8 + 1][l] = a1 + b1;
    part2[w * 8 + 2][l] = a2 + b2;
    part2[w * 8 + 3][l] = a3 + b3;
    part2[w * 8 + 4][l] = a4 + b4;
    part2[w * 8 + 5][l] = a5 + b5;
    part2[w * 8 + 6][l] = a6 + b6;
    part2[w * 8 + 7][l] = a7 + b7;
    __syncthreads();

    // combine: thread t handles shift i = 8*l + g (g = t>>6); fixed-order sum over w
    {
        const int g  = t >> 6;
        const int l2 = t & 63;
        float v = part2[g][l2];
        #pragma unroll
        for (int ww = 1; ww < 8; ++ww)
            v += part2[ww * 8 + g][l2];

        float m = v;
        #pragma unroll
        for (int d = 1; d < 64; d <<= 1)
            m = fminf(m, __shfl_xor(m, d, 64));

        if (l2 == 0) swave[g] = m;
        __syncthreads();
        if (t == 0) {
            float mm = swave[0];
            #pragma unroll
            for (int k = 1; k < 8; ++k) mm = fminf(mm, swave[k]);
            bmin[lb] = mm;
        }
    }
}

// loss = sum(bmin) / (512 * 512)
__global__ __launch_bounds__(512)
void poly_match_finalize(const float* __restrict__ bmin,
                         float* __restrict__ out)
{
    const int t = threadIdx.x;
    float v = bmin[t];
    #pragma unroll
    for (int d = 1; d < 64; d <<= 1)
        v += __shfl_xor(v, d, 64);

    __shared__ float s[8];
    if ((t & 63) == 0) s[t >> 6] = v;
    __syncthreads();
    if (t == 0) {
        float tot = 0.0f;
        #pragma unroll
        for (int k = 0; k < 8; ++k) tot += s[k];
        out[0] = tot * (1.0f / (512.0f * 512.0f));
    }
}

extern "C" void kernel_launch(void* const* d_in, const int* in_sizes, int n_in,
                              void* d_out, int out_size, void* d_ws, size_t ws_size,
                              hipStream_t stream)
{
    const float* pred = (const float*)d_in[0];  // (2,256,512,2) fp32
    const float* gt   = (const float*)d_in[1];  // (256,512,2)   fp32
    float* out  = (float*)d_out;                // scalar fp32
    float* bmin = (float*)d_ws;                 // 512 floats of scratch

    poly_match_kernel<<<LB, 512, 0, stream>>>(pred, gt, bmin);
    poly_match_finalize<<<1, PNUM, 0, stream>>>(bmin, out);
}